// Round 9
// baseline (35.980 us; speedup 1.0000x reference)
//
#include <hip/hip_runtime.h>
#include <math.h>

#define NB 32   // batch
#define CB 32   // capsule channels C
#define KC 10   // classes
#define PAD_LRT 260  // floats per lrT row
#define PAD_TP  168  // floats per Tp row

// s_part layout: s[n][c][160] (iters 0,1). Iter 2 accumulates straight into s2_sum[n][160].

// sum over c of s_part[n][c][tid] followed by squash scaling for this (k,d); tid<160
__device__ __forceinline__ float squash_term(const float* __restrict__ sp, int n, int tid) {
    const float* p = sp + (size_t)n * (CB * 160) + tid;
    float t0 = 0.f, t1 = 0.f, t2 = 0.f, t3 = 0.f;
    #pragma unroll
    for (int cc = 0; cc < 32; cc += 4) {
        t0 += p[cc * 160];       t1 += p[(cc + 1) * 160];
        t2 += p[(cc + 2) * 160]; t3 += p[(cc + 3) * 160];
    }
    float ssum = (t0 + t1) + (t2 + t3);
    float sq = ssum * ssum;
    sq += __shfl_xor(sq, 1, 16);
    sq += __shfl_xor(sq, 2, 16);
    sq += __shfl_xor(sq, 4, 16);
    sq += __shfl_xor(sq, 8, 16);
    sq = fmaxf(sq, 1e-30f);
    return ssum * sq / ((1.f + sq) * sqrtf(sq));
}

// b = lr.E, softmax over k, write c row-major [k][m=tid]
__device__ __forceinline__ void softmax_c(const float lr[16], const float* __restrict__ E,
                                          float* __restrict__ c_out, int tid) {
    float b[KC];
    #pragma unroll
    for (int k = 0; k < KC; ++k) {
        const float4* e4 = (const float4*)(E + k * 16);
        float4 e0 = e4[0], e1 = e4[1], e2 = e4[2], e3 = e4[3];
        float acc = 0.f;
        acc = fmaf(lr[0], e0.x, acc);  acc = fmaf(lr[1], e0.y, acc);
        acc = fmaf(lr[2], e0.z, acc);  acc = fmaf(lr[3], e0.w, acc);
        acc = fmaf(lr[4], e1.x, acc);  acc = fmaf(lr[5], e1.y, acc);
        acc = fmaf(lr[6], e1.z, acc);  acc = fmaf(lr[7], e1.w, acc);
        acc = fmaf(lr[8], e2.x, acc);  acc = fmaf(lr[9], e2.y, acc);
        acc = fmaf(lr[10], e2.z, acc); acc = fmaf(lr[11], e2.w, acc);
        acc = fmaf(lr[12], e3.x, acc); acc = fmaf(lr[13], e3.y, acc);
        acc = fmaf(lr[14], e3.z, acc); acc = fmaf(lr[15], e3.w, acc);
        b[k] = acc;
    }
    float mx = b[0];
    #pragma unroll
    for (int k = 1; k < KC; ++k) mx = fmaxf(mx, b[k]);
    float sum = 0.f;
    #pragma unroll
    for (int k = 0; k < KC; ++k) { b[k] = __expf(b[k] - mx); sum += b[k]; }
    const float inv = 1.f / sum;
    #pragma unroll
    for (int k = 0; k < KC; ++k) c_out[k * 256 + tid] = b[k] * inv;
}

// thread = (mg of 16 m, ij & ij+8, k-half): 28 b128 reads/thread (8 lrT + 20 c)
__device__ __forceinline__ void tp_stage(const float* __restrict__ lrTp,
                                         const float* __restrict__ cl,
                                         float* __restrict__ Tp, int tid) {
    const int mg  = tid >> 4;
    const int r   = tid & 15;
    const int ija = r & 7;
    const int ijb = ija + 8;
    const int k0  = (r >> 3) * 5;
    const float4* lp0 = (const float4*)(lrTp + ija * PAD_LRT + mg * 16);
    const float4* lp1 = (const float4*)(lrTp + ijb * PAD_LRT + mg * 16);
    float4 a0 = lp0[0], a1 = lp0[1], a2 = lp0[2], a3 = lp0[3];
    float4 b0 = lp1[0], b1 = lp1[1], b2 = lp1[2], b3 = lp1[3];
    #pragma unroll
    for (int kk = 0; kk < 5; ++kk) {
        const int k = k0 + kk;
        const float4* cp = (const float4*)(cl + k * 256 + mg * 16);
        float4 c0 = cp[0], c1 = cp[1], c2 = cp[2], c3 = cp[3];
        float t0 = 0.f, t1 = 0.f;
        t0 = fmaf(c0.x, a0.x, t0); t1 = fmaf(c0.x, b0.x, t1);
        t0 = fmaf(c0.y, a0.y, t0); t1 = fmaf(c0.y, b0.y, t1);
        t0 = fmaf(c0.z, a0.z, t0); t1 = fmaf(c0.z, b0.z, t1);
        t0 = fmaf(c0.w, a0.w, t0); t1 = fmaf(c0.w, b0.w, t1);
        t0 = fmaf(c1.x, a1.x, t0); t1 = fmaf(c1.x, b1.x, t1);
        t0 = fmaf(c1.y, a1.y, t0); t1 = fmaf(c1.y, b1.y, t1);
        t0 = fmaf(c1.z, a1.z, t0); t1 = fmaf(c1.z, b1.z, t1);
        t0 = fmaf(c1.w, a1.w, t0); t1 = fmaf(c1.w, b1.w, t1);
        t0 = fmaf(c2.x, a2.x, t0); t1 = fmaf(c2.x, b2.x, t1);
        t0 = fmaf(c2.y, a2.y, t0); t1 = fmaf(c2.y, b2.y, t1);
        t0 = fmaf(c2.z, a2.z, t0); t1 = fmaf(c2.z, b2.z, t1);
        t0 = fmaf(c2.w, a2.w, t0); t1 = fmaf(c2.w, b2.w, t1);
        t0 = fmaf(c3.x, a3.x, t0); t1 = fmaf(c3.x, b3.x, t1);
        t0 = fmaf(c3.y, a3.y, t0); t1 = fmaf(c3.y, b3.y, t1);
        t0 = fmaf(c3.z, a3.z, t0); t1 = fmaf(c3.z, b3.z, t1);
        t0 = fmaf(c3.w, a3.w, t0); t1 = fmaf(c3.w, b3.w, t1);
        Tp[mg * PAD_TP + k * 16 + ija] = t0;
        Tp[mg * PAD_TP + k * 16 + ijb] = t1;
    }
}

__device__ __forceinline__ void t_reduce(const float* __restrict__ Tp,
                                         float* __restrict__ T, int tid) {
    if (tid < 160) {
        float t = 0.f;
        #pragma unroll
        for (int mg = 0; mg < 16; ++mg) t += Tp[mg * PAD_TP + tid];
        T[tid] = t;
    }
}

// nv = 0,1: write s-partials to s_out.
// nv = 2: atomicAdd into s2_sum[n][160]; last-arriving block per n squashes + writes out.
__global__ __launch_bounds__(256) void caps_main(
    const float* __restrict__ l, const float* __restrict__ g,
    const float* __restrict__ weight,
    const float* __restrict__ sp0, const float* __restrict__ sp1,
    float* __restrict__ s_out,
    float* __restrict__ s2_sum,     // (N,160)
    int* __restrict__ ctr,          // (N)
    float* __restrict__ out,        // [a(320)|v(5120)]
    int nv)
{
    __shared__ __align__(16) float w_lds[160];
    __shared__ __align__(16) float aeff_lds[160];
    __shared__ __align__(16) float E_lds[160];
    __shared__ __align__(16) float lrT[16 * PAD_LRT];
    __shared__ __align__(16) float c_lds[KC * 256];
    __shared__ __align__(16) float Tp[16 * PAD_TP];
    __shared__ __align__(16) float T_lds[160];
    __shared__ int lastflag;

    const int tid = threadIdx.x;
    const int bid = blockIdx.x;
    const int n = bid >> 5;
    const int c = bid & 31;

    // kernel 2 (nv==1) zeroes the iter-3 accumulator + counters; visible to
    // kernel 3 across the kernel boundary (the cheap global barrier).
    if (nv == 1) {
        if (bid < 20) s2_sum[bid * 256 + tid] = 0.f;          // 5120 floats
        else if (bid == 20 && tid < 32) ctr[tid] = 0;
    }

    if (tid < 160) w_lds[tid] = weight[c * 160 + tid];

    // chain head first: squash-term global loads feed the serial aeff->E->softmax spine
    if (tid < 160) {
        float a = g[n * 160 + tid];
        if (nv > 0) a += squash_term(sp0, n, tid);
        if (nv > 1) a += squash_term(sp1, n, tid);
        aeff_lds[tid] = a;
    }

    // per-thread pose (coalesced) + transposed LDS copy
    float lr[16];
    const float* lbase = l + (size_t)bid * 4096 + tid;
    #pragma unroll
    for (int ij = 0; ij < 16; ++ij) lr[ij] = lbase[ij * 256];
    #pragma unroll
    for (int ij = 0; ij < 16; ++ij) lrT[ij * PAD_LRT + tid] = lr[ij];
    __syncthreads();                                    // S1: w, lrT, aeff ready

    if (tid < 160) {
        const int k = tid >> 4, i = (tid >> 2) & 3, j = tid & 3;
        const float4 a4 = *(const float4*)(aeff_lds + k * 16 + i * 4);
        const float4 w4 = *(const float4*)(w_lds + k * 16 + j * 4);
        E_lds[tid] = a4.x * w4.x + a4.y * w4.y + a4.z * w4.z + a4.w * w4.w;
    }
    __syncthreads();                                    // S2: E ready

    softmax_c(lr, E_lds, c_lds, tid);
    __syncthreads();                                    // S3: c ready
    tp_stage(lrT, c_lds, Tp, tid);
    __syncthreads();                                    // S4: Tp ready
    t_reduce(Tp, T_lds, tid);
    __syncthreads();                                    // S5: T ready

    if (tid < 160) {
        const int k = tid >> 4;
        const int i = (tid >> 2) & 3;
        const int le = tid & 3;
        const float4 t4 = *(const float4*)(T_lds + k * 16 + i * 4);
        float sv = 0.f;
        sv = fmaf(t4.x, w_lds[k * 16 + 0 + le], sv);
        sv = fmaf(t4.y, w_lds[k * 16 + 4 + le], sv);
        sv = fmaf(t4.z, w_lds[k * 16 + 8 + le], sv);
        sv = fmaf(t4.w, w_lds[k * 16 + 12 + le], sv);
        if (nv < 2) {
            s_out[(size_t)bid * 160 + tid] = sv;
        } else {
            // device-scope f32 atomic: coherent at L3, no L2 writeback needed
            atomicAdd(&s2_sum[n * 160 + tid], sv);
        }
    }

    if (nv != 2) return;

    // ---- fused final (iter-3 kernel only): last block per n does the squash ----
    __syncthreads();   // emits s_waitcnt vmcnt(0): this wave's & all waves' adds complete
    if (tid == 0) {
        asm volatile("s_waitcnt vmcnt(0)" ::: "memory");
        lastflag = (atomicAdd(&ctr[n], 1) == CB - 1);
    }
    __syncthreads();
    if (!lastflag) return;

    if (tid < 160) {
        // agent-scope atomic load: bypasses L1, reads the coherent point
        const float ssum = __hip_atomic_load(&s2_sum[n * 160 + tid],
                                             __ATOMIC_RELAXED, __HIP_MEMORY_SCOPE_AGENT);
        float sq = ssum * ssum;
        sq += __shfl_xor(sq, 1, 16);
        sq += __shfl_xor(sq, 2, 16);
        sq += __shfl_xor(sq, 4, 16);
        sq += __shfl_xor(sq, 8, 16);
        sq = fmaxf(sq, 1e-30f);
        const int k = tid >> 4, d = tid & 15;
        out[320 + (n * KC + k) * 16 + d] = ssum * sq / ((1.f + sq) * sqrtf(sq));
        if (d == 0) {
            const float nrm = sq / (1.f + sq);   // == ||v||
            out[n * KC + k] = 1.f / (1.f + __expf(-nrm));
        }
    }
}

extern "C" void kernel_launch(void* const* d_in, const int* in_sizes, int n_in,
                              void* d_out, int out_size, void* d_ws, size_t ws_size,
                              hipStream_t stream) {
    const float* l = (const float*)d_in[0];
    const float* g = (const float*)d_in[1];
    const float* w = (const float*)d_in[2];
    float* out = (float*)d_out;
    float* ws = (float*)d_ws;

    float* s0     = ws;                  // (N,C,160) = 163840 floats
    float* s1     = ws + 163840;         // (N,C,160)
    float* s2_sum = ws + 327680;         // (N,160) = 5120 floats
    int*   ctr    = (int*)(ws + 332800); // 32 ints

    caps_main<<<dim3(NB * CB), dim3(256), 0, stream>>>(
        l, g, w, nullptr, nullptr, s0, s2_sum, ctr, out, 0);
    caps_main<<<dim3(NB * CB), dim3(256), 0, stream>>>(
        l, g, w, s0, nullptr, s1, s2_sum, ctr, out, 1);
    caps_main<<<dim3(NB * CB), dim3(256), 0, stream>>>(
        l, g, w, s0, s1, nullptr, s2_sum, ctr, out, 2);
}

// Round 10
// 33.988 us; speedup vs baseline: 1.0586x; 1.0586x over previous
//
#include <hip/hip_runtime.h>
#include <math.h>

#define NB 32   // batch
#define CB 32   // capsule channels C
#define KC 10   // classes
#define PAD_LRT 260  // floats per lrT row
#define PAD_TP  168  // floats per Tp row

// s_part layout: s[n][c][160]

// sum over c of s_part[n][c][t], then squash scaling for this (k,d); t<160.
// Uses width-16 shuffles: caller's lane groups must align to 16 (they do).
__device__ __forceinline__ float squash_term(const float* __restrict__ sp, int n, int t) {
    const float* p = sp + (size_t)n * (CB * 160) + t;
    float t0 = 0.f, t1 = 0.f, t2 = 0.f, t3 = 0.f;
    #pragma unroll
    for (int cc = 0; cc < 32; cc += 4) {
        t0 += p[cc * 160];       t1 += p[(cc + 1) * 160];
        t2 += p[(cc + 2) * 160]; t3 += p[(cc + 3) * 160];
    }
    float ssum = (t0 + t1) + (t2 + t3);
    float sq = ssum * ssum;
    sq += __shfl_xor(sq, 1, 16);
    sq += __shfl_xor(sq, 2, 16);
    sq += __shfl_xor(sq, 4, 16);
    sq += __shfl_xor(sq, 8, 16);
    sq = fmaxf(sq, 1e-30f);
    return ssum * sq / ((1.f + sq) * sqrtf(sq));
}

// 512 threads/block: m = tid>>1, khalf = tid&1 (k in khalf*5..khalf*5+4).
__global__ __launch_bounds__(512, 8) void caps_main(
    const float* __restrict__ l, const float* __restrict__ g,
    const float* __restrict__ weight,
    const float* __restrict__ sp0, const float* __restrict__ sp1,
    float* __restrict__ s_out, int nv)
{
    __shared__ __align__(16) float w_lds[160];
    __shared__ __align__(16) float aeffA[160];   // g + squash(sp0)
    __shared__ __align__(16) float aeffB[160];   // squash(sp1) or 0
    __shared__ __align__(16) float E_lds[160];
    __shared__ __align__(16) float lrT[16 * PAD_LRT];
    __shared__ __align__(16) float c_lds[KC * 256];
    __shared__ __align__(16) float Tp[16 * PAD_TP];

    const int tid = threadIdx.x;
    const int bid = blockIdx.x;
    const int n = bid >> 5;
    const int c = bid & 31;

    // --- head: two squash chains run in DIFFERENT waves (parallel latency) ---
    if (tid < 160) {
        float a = g[n * 160 + tid];
        if (nv > 0) a += squash_term(sp0, n, tid);
        aeffA[tid] = a;
        w_lds[tid] = weight[c * 160 + tid];
    } else if (tid >= 256 && tid < 416) {
        const int t = tid - 256;
        aeffB[t] = (nv > 1) ? squash_term(sp1, n, t) : 0.f;
    }

    // lr for this thread's m (adjacent lanes share m; L1 broadcast)
    const int m  = tid >> 1;
    const int kh = tid & 1;
    float lr[16];
    {
        const float* lbase = l + (size_t)bid * 4096 + m;
        #pragma unroll
        for (int ij = 0; ij < 16; ++ij) lr[ij] = lbase[ij * 256];
        if (kh == 0) {
            #pragma unroll
            for (int ij = 0; ij < 16; ++ij) lrT[ij * PAD_LRT + m] = lr[ij];
        }
    }
    __syncthreads();                                    // S1: w, aeffA/B, lrT

    // E[k][i][j] = sum_l (aeffA+aeffB)[k][i4+l] * w[k][j4+l]
    if (tid < 160) {
        const int k = tid >> 4, i = (tid >> 2) & 3, j = tid & 3;
        const float4 a4 = *(const float4*)(aeffA + k * 16 + i * 4);
        const float4 b4 = *(const float4*)(aeffB + k * 16 + i * 4);
        const float4 w4 = *(const float4*)(w_lds + k * 16 + j * 4);
        E_lds[tid] = (a4.x + b4.x) * w4.x + (a4.y + b4.y) * w4.y
                   + (a4.z + b4.z) * w4.z + (a4.w + b4.w) * w4.w;
    }
    __syncthreads();                                    // S2: E ready

    // softmax over k, k-split across lane pairs: 5 dots + 5 exp per thread
    {
        float b[5];
        #pragma unroll
        for (int kk = 0; kk < 5; ++kk) {
            const int k = kh * 5 + kk;
            const float4* e4 = (const float4*)(E_lds + k * 16);
            float4 e0 = e4[0], e1 = e4[1], e2 = e4[2], e3 = e4[3];
            float acc = 0.f;
            acc = fmaf(lr[0], e0.x, acc);  acc = fmaf(lr[1], e0.y, acc);
            acc = fmaf(lr[2], e0.z, acc);  acc = fmaf(lr[3], e0.w, acc);
            acc = fmaf(lr[4], e1.x, acc);  acc = fmaf(lr[5], e1.y, acc);
            acc = fmaf(lr[6], e1.z, acc);  acc = fmaf(lr[7], e1.w, acc);
            acc = fmaf(lr[8], e2.x, acc);  acc = fmaf(lr[9], e2.y, acc);
            acc = fmaf(lr[10], e2.z, acc); acc = fmaf(lr[11], e2.w, acc);
            acc = fmaf(lr[12], e3.x, acc); acc = fmaf(lr[13], e3.y, acc);
            acc = fmaf(lr[14], e3.z, acc); acc = fmaf(lr[15], e3.w, acc);
            b[kk] = acc;
        }
        float mx = b[0];
        #pragma unroll
        for (int kk = 1; kk < 5; ++kk) mx = fmaxf(mx, b[kk]);
        mx = fmaxf(mx, __shfl_xor(mx, 1, 64));          // combine the two k-halves
        float sum = 0.f;
        #pragma unroll
        for (int kk = 0; kk < 5; ++kk) { b[kk] = __expf(b[kk] - mx); sum += b[kk]; }
        sum += __shfl_xor(sum, 1, 64);
        const float inv = 1.f / sum;
        #pragma unroll
        for (int kk = 0; kk < 5; ++kk)
            c_lds[(kh * 5 + kk) * 256 + m] = b[kk] * inv;
    }
    __syncthreads();                                    // S3: c ready

    // Tp[mg][k*16+ij] = sum_{m in group mg} c[k][m]*lrT[ij][m]
    // thread = (mg = tid>>5, ij = (tid>>1)&15, kh2 = tid&1): 24 b128 reads
    {
        const int mg  = tid >> 5;
        const int ij  = (tid >> 1) & 15;
        const int kh2 = tid & 1;
        const float4* lp = (const float4*)(lrT + ij * PAD_LRT + mg * 16);
        float4 a0 = lp[0], a1 = lp[1], a2 = lp[2], a3 = lp[3];
        #pragma unroll
        for (int kk = 0; kk < 5; ++kk) {
            const int k = kh2 * 5 + kk;
            const float4* cp = (const float4*)(c_lds + k * 256 + mg * 16);
            float4 c0 = cp[0], c1 = cp[1], c2 = cp[2], c3 = cp[3];
            float t = 0.f;
            t = fmaf(c0.x, a0.x, t); t = fmaf(c0.y, a0.y, t);
            t = fmaf(c0.z, a0.z, t); t = fmaf(c0.w, a0.w, t);
            t = fmaf(c1.x, a1.x, t); t = fmaf(c1.y, a1.y, t);
            t = fmaf(c1.z, a1.z, t); t = fmaf(c1.w, a1.w, t);
            t = fmaf(c2.x, a2.x, t); t = fmaf(c2.y, a2.y, t);
            t = fmaf(c2.z, a2.z, t); t = fmaf(c2.w, a2.w, t);
            t = fmaf(c3.x, a3.x, t); t = fmaf(c3.y, a3.y, t);
            t = fmaf(c3.w, a3.w, t); t = fmaf(c3.z, a3.z, t);
            Tp[mg * PAD_TP + k * 16 + ij] = t;
        }
    }
    __syncthreads();                                    // S4: Tp ready

    // merged T-reduce + s-write: sv = sum_mg sum_j Tp[mg][k16+i4+j]*w[k][j4+le]
    if (tid < 160) {
        const int k = tid >> 4;
        const int i = (tid >> 2) & 3;
        const int le = tid & 3;
        const float w0 = w_lds[k * 16 + 0  + le];
        const float w1 = w_lds[k * 16 + 4  + le];
        const float w2 = w_lds[k * 16 + 8  + le];
        const float w3 = w_lds[k * 16 + 12 + le];
        float sv = 0.f;
        #pragma unroll
        for (int mg = 0; mg < 16; ++mg) {
            const float4 t4 = *(const float4*)(Tp + mg * PAD_TP + k * 16 + i * 4);
            sv = fmaf(t4.x, w0, sv);
            sv = fmaf(t4.y, w1, sv);
            sv = fmaf(t4.z, w2, sv);
            sv = fmaf(t4.w, w3, sv);
        }
        s_out[(size_t)bid * 160 + tid] = sv;
    }
}

// final: v = squash(sum_c s2), a = sigmoid(||v||); out = [a(320) | v(5120)]
__global__ __launch_bounds__(256) void caps_final(
    const float* __restrict__ sp2, float* __restrict__ out)
{
    const int idx = blockIdx.x * 256 + threadIdx.x;  // 0..5119
    const int nk = idx >> 4;
    const int d = idx & 15;
    const int n = nk / 10;
    const int k = nk - n * 10;
    const float* sp = sp2 + (size_t)n * (CB * 160) + k * 16 + d;
    float t0 = 0.f, t1 = 0.f, t2 = 0.f, t3 = 0.f;
    #pragma unroll
    for (int cc = 0; cc < 32; cc += 4) {
        t0 += sp[cc * 160];       t1 += sp[(cc + 1) * 160];
        t2 += sp[(cc + 2) * 160]; t3 += sp[(cc + 3) * 160];
    }
    float ssum = (t0 + t1) + (t2 + t3);
    float sq = ssum * ssum;
    sq += __shfl_xor(sq, 1, 16);
    sq += __shfl_xor(sq, 2, 16);
    sq += __shfl_xor(sq, 4, 16);
    sq += __shfl_xor(sq, 8, 16);
    sq = fmaxf(sq, 1e-30f);
    out[320 + nk * 16 + d] = ssum * sq / ((1.f + sq) * sqrtf(sq));
    if (d == 0) {
        const float nrm = sq / (1.f + sq);   // == ||v||
        out[nk] = 1.f / (1.f + __expf(-nrm));
    }
}

extern "C" void kernel_launch(void* const* d_in, const int* in_sizes, int n_in,
                              void* d_out, int out_size, void* d_ws, size_t ws_size,
                              hipStream_t stream) {
    const float* l = (const float*)d_in[0];
    const float* g = (const float*)d_in[1];
    const float* w = (const float*)d_in[2];
    float* out = (float*)d_out;
    float* ws = (float*)d_ws;

    float* s0 = ws;                 // (N,C,160) = 163840 floats each
    float* s1 = ws + 163840;
    float* s2 = ws + 327680;

    caps_main<<<dim3(NB * CB), dim3(512), 0, stream>>>(l, g, w, nullptr, nullptr, s0, 0);
    caps_main<<<dim3(NB * CB), dim3(512), 0, stream>>>(l, g, w, s0, nullptr, s1, 1);
    caps_main<<<dim3(NB * CB), dim3(512), 0, stream>>>(l, g, w, s0, s1, s2, 2);
    caps_final<<<dim3(20), dim3(256), 0, stream>>>(s2, out);
}